// Round 7
// baseline (242.889 us; speedup 1.0000x reference)
//
#include <hip/hip_runtime.h>
#include <float.h>
#include <limits.h>

// Codebook / VQ: x [65536][256] fp32, codes [1024][256] fp32
// out: quantized [65536][256] fp32, then indices [65536] as fp32 values.
// Tiered: fp16 MFMA GEMM argmin (all rows) -> fp32 rescue (gap<EPS1 rows)
//        -> fp64+DELTA smallest-index rescue (gap<EPS2 rows).
// Round 7: NO-LDS register-pipelined main kernel. Round-6 PMC: occupancy is
// grid-capped at 2 waves/SIMD (2048 waves total at 32 rows/wave) and ~75% of
// wall time was __syncthreads vmcnt(0) drain + per-chunk latency chain.
// Fix: drop LDS staging + barriers entirely; A-frags load global->VGPR with
// half-chunk software pipelining (load H(n+1) || MFMA H(n)) so the compiler
// emits counted vmcnt(8) (round 4 lacked the rotation -> full drains).
// Regs: xf 64 + fa/fb 64 + acc 32(AGPR) + temps ~= 185 <= 256 @ (256,2).
#define D     256
#define C     1024
#define EPS1  0.45f     // fp16-MFMA gap flag: 0.3 (fp16 err) + 0.125 (key truncation) + slack
#define EPS2  0.02f     // fp32 gap flag (proven)
#define DELTA 1.0e-4    // np ulp-collision window on exact fp64 distances
#define BR    8         // rows per batch in fp32 rescue

typedef _Float16 half8 __attribute__((ext_vector_type(8)));
typedef _Float16 half4_t __attribute__((ext_vector_type(4)));
typedef float f32x16 __attribute__((ext_vector_type(16)));

static __device__ __forceinline__ unsigned umin_(unsigned a, unsigned b) { return a < b ? a : b; }
static __device__ __forceinline__ unsigned umax_(unsigned a, unsigned b) { return a > b ? a : b; }

// prep: cnorm fp32 (+biased copy), codes -> fp16 tiled (32x32x16 A-frag
// layout), codes -> fp32 transpose, zero counters.
// Tiled layout (HW-verified round 6, absmax=0): value codes[c][k] at
//   codes_h[(c>>5)*8192 + (k>>4)*512 + ((c&31) + 32*((k>>3)&1))*8 + (k&7)]
// => A-frag for (chunk ct, ks) as half8[]: codes_h8[ct*1024 + ks*64 + lane],
// lane l holding code (l&31), k = ks*16 + (l>>5)*8 + j.
__global__ __launch_bounds__(256)
void prep(const float* __restrict__ codes, float* __restrict__ cnorm,
          float* __restrict__ cnormb,
          _Float16* __restrict__ codes_h, float* __restrict__ codes_t,
          int* __restrict__ count1, int* __restrict__ count2) {
    if (blockIdx.x == 0 && threadIdx.x == 0) { *count1 = 0; *count2 = 0; }
    int c    = (blockIdx.x * blockDim.x + threadIdx.x) >> 6;   // 0..1023, one code per wave
    int lane = threadIdx.x & 63;
    float4 v = ((const float4*)(codes + (size_t)c * D))[lane]; // k = 4*lane..4*lane+3
    half4_t h; h[0] = (_Float16)v.x; h[1] = (_Float16)v.y; h[2] = (_Float16)v.z; h[3] = (_Float16)v.w;
    {
        int ks = lane >> 2;              // (4*lane)>>4
        int kb = (lane >> 1) & 1;        // ((4*lane)>>3)&1
        int e  = (lane & 1) * 4;         // (4*lane)&7
        size_t off = (size_t)(c >> 5) * 8192 + ks * 512 + ((c & 31) + 32 * kb) * 8 + e;
        *(half4_t*)(codes_h + off) = h;
    }
    // fp32 transpose codes_t[k][c]
    codes_t[(size_t)(4*lane+0) * C + c] = v.x;
    codes_t[(size_t)(4*lane+1) * C + c] = v.y;
    codes_t[(size_t)(4*lane+2) * C + c] = v.z;
    codes_t[(size_t)(4*lane+3) * C + c] = v.w;
    float s = v.x * v.x + v.y * v.y + v.z * v.z + v.w * v.w;
    #pragma unroll
    for (int off = 32; off >= 1; off >>= 1) s += __shfl_xor(s, off, 64);
    if (lane == 0) { cnorm[c] = s; cnormb[c] = s + 1024.0f; }
}

// ---- main: fp16 32x32x16 MFMA distance argmin, no LDS, no barriers ----
// mfma(A=codes[32c x 16k], B=x[16k x 32rows]) -> D[code][xrow]:
// col=lane&31 = xrow (lane-local argmin), code=(reg&3)+8*(reg>>2)+4*(lane>>5).
// A-frags stream global(L2)->VGPR, half-chunk double-buffered (fa/fb) so 8
// loads stay in flight across each 8-MFMA group (counted vmcnt, no drains).
// Packed key: trunc-score(22b) | code-index(10b); u32 min = lexicographic.
__global__ __launch_bounds__(256, 2)
void codebook_mfma(const float* __restrict__ x, const _Float16* __restrict__ codes_h,
                   const float* __restrict__ codes, const float* __restrict__ cnormb,
                   float* __restrict__ out_q, float* __restrict__ out_i,
                   int* __restrict__ count1, int* __restrict__ rowlist1) {
    const int tid  = threadIdx.x;
    const int w    = tid >> 6, lane = tid & 63;
    const int l31  = lane & 31, hi = lane >> 5;
    const int row0 = blockIdx.x * 128;        // 4 independent waves x 32 rows
    const int myrow = row0 + w * 32 + l31;    // the ONE x-row this lane scores

    // x fragments: xf[ks] holds k = ks*16 + hi*8 + 0..7 of myrow (64 VGPRs)
    const float* xp = x + (size_t)myrow * D + hi * 8;
    half8 xf[16];
    #pragma unroll
    for (int ks = 0; ks < 16; ++ks) {
        float4 a = *(const float4*)(xp + ks * 16);
        float4 b = *(const float4*)(xp + ks * 16 + 4);
        half8 h;
        h[0]=(_Float16)a.x; h[1]=(_Float16)a.y; h[2]=(_Float16)a.z; h[3]=(_Float16)a.w;
        h[4]=(_Float16)b.x; h[5]=(_Float16)b.y; h[6]=(_Float16)b.z; h[7]=(_Float16)b.w;
        xf[ks] = h;
    }

    // A-frag stream: codes_h as half8[]; frag(ct, ks) at [ct*1024 + ks*64 + lane]
    const half8* ab = (const half8*)codes_h + lane;

    unsigned K1 = 0xFFFFFFFFu, K2 = 0xFFFFFFFFu;   // per-lane top-2 for myrow

    half8 fa[8], fb[8];
    // preload chunk 0, half H0 (ks 0..7)
    #pragma unroll
    for (int j = 0; j < 8; ++j) fa[j] = ab[j * 64];

    for (int ct = 0; ct < 32; ++ct) {              // 32 chunks of 32 codes
        const half8* base = ab + ct * 1024;

        // issue loads for H1 of this chunk (ks 8..15)
        #pragma unroll
        for (int j = 0; j < 8; ++j) fb[j] = base[(8 + j) * 64];

        f32x16 accA, accB;
        #pragma unroll
        for (int i = 0; i < 16; ++i) { accA[i] = 0.f; accB[i] = 0.f; }

        // MFMA on H0 (fa) while fb loads are in flight
        #pragma unroll
        for (int j = 0; j < 8; j += 2) {
            accA = __builtin_amdgcn_mfma_f32_32x32x16_f16(fa[j],     xf[j],     accA, 0, 0, 0);
            accB = __builtin_amdgcn_mfma_f32_32x32x16_f16(fa[j + 1], xf[j + 1], accB, 0, 0, 0);
        }

        // issue loads for H0 of next chunk
        if (ct < 31) {
            #pragma unroll
            for (int j = 0; j < 8; ++j) fa[j] = base[1024 + j * 64];
        }

        // MFMA on H1 (fb) while fa loads are in flight
        #pragma unroll
        for (int j = 8; j < 16; j += 2) {
            accA = __builtin_amdgcn_mfma_f32_32x32x16_f16(fb[j - 8], xf[j],     accA, 0, 0, 0);
            accB = __builtin_amdgcn_mfma_f32_32x32x16_f16(fb[j - 7], xf[j + 1], accB, 0, 0, 0);
        }

        // codes this lane holds: cb + g*8 + j, cb = ct*32 + hi*4
        const int cb = ct * 32 + hi * 4;
        #pragma unroll
        for (int g = 0; g < 4; ++g) {
            float4 cn = *(const float4*)(cnormb + cb + g * 8);
            const unsigned base_i = (unsigned)(cb + g * 8);
            float s0 = fmaf(-2.f, accA[g*4+0], fmaf(-2.f, accB[g*4+0], cn.x));
            float s1 = fmaf(-2.f, accA[g*4+1], fmaf(-2.f, accB[g*4+1], cn.y));
            float s2 = fmaf(-2.f, accA[g*4+2], fmaf(-2.f, accB[g*4+2], cn.z));
            float s3 = fmaf(-2.f, accA[g*4+3], fmaf(-2.f, accB[g*4+3], cn.w));
            unsigned k0 = (__float_as_uint(s0) & 0xFFFFFC00u) | base_i;
            unsigned k1 = (__float_as_uint(s1) & 0xFFFFFC00u) | (base_i + 1u);
            unsigned k2 = (__float_as_uint(s2) & 0xFFFFFC00u) | (base_i + 2u);
            unsigned k3 = (__float_as_uint(s3) & 0xFFFFFC00u) | (base_i + 3u);
            unsigned lo01 = umin_(k0, k1), hi01 = umax_(k0, k1);
            unsigned lo23 = umin_(k2, k3), hi23 = umax_(k2, k3);
            unsigned best = umin_(lo01, lo23);
            unsigned mid  = umax_(lo01, lo23);
            unsigned sec  = umin_(umin_(hi01, hi23), mid);
            unsigned tt   = umax_(K1, best);
            K2 = umin_(umin_(K2, sec), tt);
            K1 = umin_(K1, best);
        }
    }

    // merge lanes l and l+32 (same x-row, disjoint code sets)
    {
        unsigned o1 = (unsigned)__shfl_xor((int)K1, 32, 64);
        unsigned o2 = (unsigned)__shfl_xor((int)K2, 32, 64);
        unsigned tt = umax_(K1, o1);
        K2 = umin_(umin_(K2, o2), tt);
        K1 = umin_(K1, o1);
    }

    // winner + gap flag (lanes 0..31 own the wave's 32 rows)
    if (lane < 32) {
        out_i[myrow] = (float)(K1 & 0x3FFu);
        float g1 = __uint_as_float(K1 & 0xFFFFFC00u);
        float g2 = __uint_as_float(K2 & 0xFFFFFC00u);
        if (g2 - g1 < EPS1) {
            int s = atomicAdd(count1, 1);
            rowlist1[s] = myrow;
        }
    }

    // gather quantized rows: wave writes its own 32 rows, fully coalesced
    const float4* c4 = (const float4*)codes;
    float4* q4 = (float4*)out_q + (size_t)(row0 + w * 32) * 64;
    #pragma unroll 4
    for (int r = 0; r < 32; ++r) {
        int wi = __shfl((int)K1, r, 64) & 0x3FF;   // lane r holds row r's winner
        q4[(size_t)r * 64 + lane] = c4[(size_t)wi * 64 + lane];
    }
}

// ---- tier-1: fp32 rescore of flagged rows, BR rows/block share codes stream ----
__global__ __launch_bounds__(256)
void rescue32(const float* __restrict__ x, const float* __restrict__ codes,
              const float* __restrict__ codes_t, const float* __restrict__ cnorm,
              const int* __restrict__ count1, const int* __restrict__ rowlist1,
              float* __restrict__ out_q, float* __restrict__ out_i,
              int* __restrict__ count2, int* __restrict__ rowlist2) {
    __shared__ __align__(16) float xr[BR][D];    // 8 KB
    __shared__ int rows_s[BR];
    __shared__ int winc_s[BR];
    __shared__ float wm1[BR][4], wm2[BR][4];
    __shared__ int wi_[BR][4];
    const int t = threadIdx.x;
    const int w = t >> 6, lane = t & 63;
    const int n1 = *count1;
    if (n1 == 0) return;
    const int nb = (n1 + BR - 1) / BR;
    const float4* ct4 = (const float4*)codes_t;  // [k][c/4]

    for (int b = blockIdx.x; b < nb; b += gridDim.x) {
        __syncthreads();
        if (t < BR) {
            int idx = b * BR + t;
            if (idx >= n1) idx = n1 - 1;           // duplicate tail rows (benign)
            rows_s[t] = rowlist1[idx];
        }
        __syncthreads();
        #pragma unroll
        for (int p = 0; p < BR * 64 / 256; ++p) {  // 2 iters
            int flat = p * 256 + t;
            int r = flat >> 6, q = flat & 63;
            ((float4*)&xr[r][0])[q] = ((const float4*)x)[(size_t)rows_s[r] * 64 + q];
        }
        __syncthreads();

        float acc[BR][4];                          // 32 VGPRs: fits, no spill
        #pragma unroll
        for (int r = 0; r < BR; ++r)
            #pragma unroll
            for (int j = 0; j < 4; ++j) acc[r][j] = 0.f;

        for (int k = 0; k < D; k += 4) {
            float4 cv0 = ct4[(size_t)(k+0) * 256 + t];
            float4 cv1 = ct4[(size_t)(k+1) * 256 + t];
            float4 cv2 = ct4[(size_t)(k+2) * 256 + t];
            float4 cv3 = ct4[(size_t)(k+3) * 256 + t];
            #pragma unroll
            for (int r = 0; r < BR; ++r) {
                float4 xv = *(const float4*)&xr[r][k];
                acc[r][0] = fmaf(xv.x, cv0.x, acc[r][0]);
                acc[r][1] = fmaf(xv.x, cv0.y, acc[r][1]);
                acc[r][2] = fmaf(xv.x, cv0.z, acc[r][2]);
                acc[r][3] = fmaf(xv.x, cv0.w, acc[r][3]);
                acc[r][0] = fmaf(xv.y, cv1.x, acc[r][0]);
                acc[r][1] = fmaf(xv.y, cv1.y, acc[r][1]);
                acc[r][2] = fmaf(xv.y, cv1.z, acc[r][2]);
                acc[r][3] = fmaf(xv.y, cv1.w, acc[r][3]);
                acc[r][0] = fmaf(xv.z, cv2.x, acc[r][0]);
                acc[r][1] = fmaf(xv.z, cv2.y, acc[r][1]);
                acc[r][2] = fmaf(xv.z, cv2.z, acc[r][2]);
                acc[r][3] = fmaf(xv.z, cv2.w, acc[r][3]);
                acc[r][0] = fmaf(xv.w, cv3.x, acc[r][0]);
                acc[r][1] = fmaf(xv.w, cv3.y, acc[r][1]);
                acc[r][2] = fmaf(xv.w, cv3.z, acc[r][2]);
                acc[r][3] = fmaf(xv.w, cv3.w, acc[r][3]);
            }
        }

        // per-thread top-2-of-4 + in-wave butterfly, all rows, no barriers
        float cn0 = cnorm[4*t+0], cn1 = cnorm[4*t+1], cn2 = cnorm[4*t+2], cn3 = cnorm[4*t+3];
        #pragma unroll
        for (int r = 0; r < BR; ++r) {
            float s0 = fmaf(-2.f, acc[r][0], cn0);
            float s1 = fmaf(-2.f, acc[r][1], cn1);
            float s2 = fmaf(-2.f, acc[r][2], cn2);
            float s3 = fmaf(-2.f, acc[r][3], cn3);
            float lm1 = s0; int li = 4*t;
            float lm2 = FLT_MAX;
            if (s1 < lm1) { lm2 = lm1; lm1 = s1; li = 4*t+1; } else lm2 = s1;
            if (s2 < lm1) { lm2 = lm1; lm1 = s2; li = 4*t+2; } else lm2 = fminf(lm2, s2);
            if (s3 < lm1) { lm2 = lm1; lm1 = s3; li = 4*t+3; } else lm2 = fminf(lm2, s3);
            #pragma unroll
            for (int off = 1; off < 64; off <<= 1) {
                float o1 = __shfl_xor(lm1, off, 64);
                float o2 = __shfl_xor(lm2, off, 64);
                int   oi = __shfl_xor(li,  off, 64);
                if (o1 < lm1 || (o1 == lm1 && oi < li)) { lm2 = fminf(lm1, o2); lm1 = o1; li = oi; }
                else lm2 = fminf(lm2, o1);
            }
            if (lane == 0) { wm1[r][w] = lm1; wm2[r][w] = lm2; wi_[r][w] = li; }
        }
        __syncthreads();
        if (t < BR) {
            float b1 = wm1[t][0], b2 = wm2[t][0]; int bi = wi_[t][0];
            #pragma unroll
            for (int ww = 1; ww < 4; ++ww) {
                float o1 = wm1[t][ww], o2 = wm2[t][ww]; int oi = wi_[t][ww];
                if (o1 < b1 || (o1 == b1 && oi < bi)) { b2 = fminf(b1, o2); b1 = o1; bi = oi; }
                else b2 = fminf(b2, o1);
            }
            const int rg = rows_s[t];
            out_i[rg] = (float)bi;
            winc_s[t] = bi;
            if (b2 - b1 < EPS2) {
                int s = atomicAdd(count2, 1);
                rowlist2[s] = rg;
            }
        }
        __syncthreads();
        // gather quantized rows
        #pragma unroll
        for (int p = 0; p < BR * 64 / 256; ++p) {
            int flat = p * 256 + t;
            int r = flat >> 6, q = flat & 63;
            float4 v = ((const float4*)codes)[(size_t)winc_s[r] * 64 + q];
            ((float4*)out_q)[(size_t)rows_s[r] * 64 + q] = v;
        }
        __syncthreads();
    }
}

// ---- tier-2: exact fp64 rescore; smallest index within DELTA ----
__global__ __launch_bounds__(256)
void rescue_exact(const float* __restrict__ x, const float* __restrict__ codes,
                  const int* __restrict__ count, const int* __restrict__ rowlist,
                  float* __restrict__ out_q, float* __restrict__ out_i) {
    __shared__ float  xrow[D];
    __shared__ double dbuf[C];
    __shared__ double rmin[256];
    __shared__ int    ridx[256];
    const int t = threadIdx.x;
    const int n = *count;
    for (int idx = blockIdx.x; idx < n; idx += gridDim.x) {
        const int row = rowlist[idx];
        __syncthreads();
        xrow[t] = x[(size_t)row * D + t];
        __syncthreads();
        double lmin = 1e300;
        #pragma unroll
        for (int j = 0; j < 4; ++j) {
            const int c = 4 * t + j;
            const float* cp = codes + (size_t)c * D;
            double s = 0.0;
            for (int k = 0; k < D; k += 4) {
                float4 cv = *(const float4*)(cp + k);
                double d0 = (double)xrow[k+0] - (double)cv.x;
                double d1 = (double)xrow[k+1] - (double)cv.y;
                double d2 = (double)xrow[k+2] - (double)cv.z;
                double d3 = (double)xrow[k+3] - (double)cv.w;
                s += d0*d0 + d1*d1 + d2*d2 + d3*d3;
            }
            dbuf[c] = s;
            lmin = fmin(lmin, s);
        }
        rmin[t] = lmin;
        __syncthreads();
        for (int sft = 128; sft > 0; sft >>= 1) {
            if (t < sft) rmin[t] = fmin(rmin[t], rmin[t + sft]);
            __syncthreads();
        }
        const double dstar = rmin[0];
        int lidx = INT_MAX;
        #pragma unroll
        for (int j = 0; j < 4; ++j) {
            const int c = 4 * t + j;
            if (dbuf[c] < dstar + DELTA && c < lidx) lidx = c;
        }
        ridx[t] = lidx;
        __syncthreads();
        for (int sft = 128; sft > 0; sft >>= 1) {
            if (t < sft) ridx[t] = min(ridx[t], ridx[t + sft]);
            __syncthreads();
        }
        const int winc = ridx[0];
        if (t == 0) out_i[row] = (float)winc;
        if (t < 64) {
            float4 cv = ((const float4*)(codes + (size_t)winc * D))[t];
            ((float4*)(out_q + (size_t)row * D))[t] = cv;
        }
        __syncthreads();
    }
}

extern "C" void kernel_launch(void* const* d_in, const int* in_sizes, int n_in,
                              void* d_out, int out_size, void* d_ws, size_t ws_size,
                              hipStream_t stream) {
    const float* x     = (const float*)d_in[0];
    const float* codes = (const float*)d_in[1];
    const int N = in_sizes[0] / D;                 // 65536

    char* ws = (char*)d_ws;
    float*    cnorm   = (float*)ws;                       ws += C * 4;              // 4 KB
    float*    cnormb  = (float*)ws;                       ws += C * 4;              // 4 KB (biased +1024)
    float*    codes_t = (float*)ws;                       ws += (size_t)D * C * 4;  // 1 MB
    _Float16* codes_h = (_Float16*)ws;                    ws += (size_t)C * D * 2;  // 512 KB (tiled)
    int*      count1  = (int*)ws;                         ws += 16;
    int*      count2  = (int*)ws;                         ws += 16;
    int*      rowlist1 = (int*)ws;                        ws += (size_t)N * 4;
    int*      rowlist2 = (int*)ws;

    float* out_q = (float*)d_out;
    float* out_i = out_q + (size_t)N * D;

    prep<<<C / 4, 256, 0, stream>>>(codes, cnorm, cnormb, codes_h, codes_t, count1, count2);
    codebook_mfma<<<N / 128, 256, 0, stream>>>(x, codes_h, codes, cnormb,
                                               out_q, out_i, count1, rowlist1);
    rescue32<<<2048, 256, 0, stream>>>(x, codes, codes_t, cnorm, count1, rowlist1,
                                       out_q, out_i, count2, rowlist2);
    rescue_exact<<<256, 256, 0, stream>>>(x, codes, count2, rowlist2, out_q, out_i);
}

// Round 8
// 212.376 us; speedup vs baseline: 1.1437x; 1.1437x over previous
//
#include <hip/hip_runtime.h>
#include <float.h>
#include <limits.h>

// Codebook / VQ: x [65536][256] fp32, codes [1024][256] fp32
// out: quantized [65536][256] fp32, then indices [65536] as fp32 values.
// Tiered: fp16 MFMA GEMM argmin (all rows) -> fp32 rescue (gap<EPS1 rows)
//        -> fp64+DELTA smallest-index rescue (gap<EPS2 rows).
// Round 8: main kernel REVERTED to the round-5 proven version (70 us; rounds
// 6/7 alternatives measured 78/83). New work this round is in the rescue
// tier, which the totals show costs ~160 us across rounds 5-7:
//   rescue_exact read codes[4t+j][k] with 4096B lane stride -> 64 cache
//   lines per wave-load, ~64 TA-cyc each, ~25 us per flagged row regardless
//   of n2. Fix: read via codes_t[k][4t..4t+3] (coalesced float4), identical
//   fp64 math. Grid 256 -> 1024.
#define D     256
#define C     1024
#define EPS1  0.45f     // fp16-MFMA gap flag: 0.3 (fp16 err) + 0.125 (key truncation) + slack
#define EPS2  0.02f     // fp32 gap flag (proven)
#define DELTA 1.0e-4    // np ulp-collision window on exact fp64 distances
#define BR    8         // rows per batch in fp32 rescue

typedef _Float16 half8 __attribute__((ext_vector_type(8)));
typedef _Float16 half4_t __attribute__((ext_vector_type(4)));
typedef float v4f __attribute__((ext_vector_type(4)));

typedef const __attribute__((address_space(1))) void g_void;
typedef __attribute__((address_space(3))) void l_void;

static __device__ __forceinline__ unsigned umin_(unsigned a, unsigned b) { return a < b ? a : b; }
static __device__ __forceinline__ unsigned umax_(unsigned a, unsigned b) { return a > b ? a : b; }

// prep: cnorm fp32 (+biased copy), codes -> fp16 TILED copy (16-code tiles,
// round-5 layout, HW-verified), codes -> fp32 transpose, zero counters.
// Tiled fp16 layout: value codes[c][k] at
//   codes_h[(c>>4)*4096 + (k>>5)*512 + (((k>>3)&3)*16 + (c&15))*8 + (k&7)]
__global__ __launch_bounds__(256)
void prep(const float* __restrict__ codes, float* __restrict__ cnorm,
          float* __restrict__ cnormb,
          _Float16* __restrict__ codes_h, float* __restrict__ codes_t,
          int* __restrict__ count1, int* __restrict__ count2) {
    if (blockIdx.x == 0 && threadIdx.x == 0) { *count1 = 0; *count2 = 0; }
    int c    = (blockIdx.x * blockDim.x + threadIdx.x) >> 6;   // 0..1023, one code per wave
    int lane = threadIdx.x & 63;
    float4 v = ((const float4*)(codes + (size_t)c * D))[lane]; // k = 4*lane..4*lane+3
    half4_t h; h[0] = (_Float16)v.x; h[1] = (_Float16)v.y; h[2] = (_Float16)v.z; h[3] = (_Float16)v.w;
    {
        int kc   = lane >> 3;            // (4*lane)>>5
        int quad = (lane >> 1) & 3;      // ((4*lane)>>3)&3
        int e    = (lane & 1) * 4;       // (4*lane)&7
        size_t off = (size_t)(c >> 4) * 4096 + kc * 512 + (quad * 16 + (c & 15)) * 8 + e;
        *(half4_t*)(codes_h + off) = h;
    }
    // fp32 transpose codes_t[k][c]
    codes_t[(size_t)(4*lane+0) * C + c] = v.x;
    codes_t[(size_t)(4*lane+1) * C + c] = v.y;
    codes_t[(size_t)(4*lane+2) * C + c] = v.z;
    codes_t[(size_t)(4*lane+3) * C + c] = v.w;
    float s = v.x * v.x + v.y * v.y + v.z * v.z + v.w * v.w;
    #pragma unroll
    for (int off = 32; off >= 1; off >>= 1) s += __shfl_xor(s, off, 64);
    if (lane == 0) { cnorm[c] = s; cnormb[c] = s + 1024.0f; }
}

// ---- main: fp16 MFMA distance argmin (ROUND-5 PROVEN VERSION, 70 us) ----
// 64 rows/block, 16 rows per wave; mfma(A=codes_tile, B=x_frag) ->
// C[code][xrow], col=lane&15 = xrow (lane-local argmin).
// Codes double-buffered in LDS: chunk = 32 codes = 16 KB via global_load_lds.
__global__ __launch_bounds__(256, 4)
void codebook_mfma(const float* __restrict__ x, const _Float16* __restrict__ codes_h,
                   const float* __restrict__ codes, const float* __restrict__ cnormb,
                   float* __restrict__ out_q, float* __restrict__ out_i,
                   int* __restrict__ count1, int* __restrict__ rowlist1) {
    __shared__ __align__(16) _Float16 Bs[2][8192];   // 2 x 16 KB: 32 codes x 256 k

    const int tid  = threadIdx.x;
    const int wy   = tid >> 6, lane = tid & 63;
    const int quad = lane >> 4, l15 = lane & 15;
    const int row0 = blockIdx.x * 64;
    const int myrow = row0 + wy * 16 + l15;   // the ONE x-row this lane scores

    // stage chunk 0 (16 KB): 4 x 16B per thread, linear
    {
        const char* g = (const char*)codes_h;
        char* l = (char*)&Bs[0][0];
        #pragma unroll
        for (int p = 0; p < 4; ++p) {
            const int off = (p * 256 + tid) * 16;
            __builtin_amdgcn_global_load_lds((g_void*)(g + off), (l_void*)(l + off), 16, 0, 0);
        }
    }

    // this wave's 16 x-rows -> registers as fp16 B-fragments (32 VGPRs)
    const float* xp = x + (size_t)myrow * D + quad * 8;
    half8 xf[8];
    #pragma unroll
    for (int kc = 0; kc < 8; ++kc) {
        float4 a = *(const float4*)(xp + kc * 32);
        float4 b = *(const float4*)(xp + kc * 32 + 4);
        half8 h;
        h[0]=(_Float16)a.x; h[1]=(_Float16)a.y; h[2]=(_Float16)a.z; h[3]=(_Float16)a.w;
        h[4]=(_Float16)b.x; h[5]=(_Float16)b.y; h[6]=(_Float16)b.z; h[7]=(_Float16)b.w;
        xf[kc] = h;
    }

    unsigned K1 = 0xFFFFFFFFu, K2 = 0xFFFFFFFFu;   // per-lane top-2 for myrow
    __syncthreads();   // chunk 0 staged

    for (int ct = 0; ct < 32; ++ct) {              // 32 chunks of 32 codes
        const int cur = ct & 1;
        if (ct < 31) {                             // prefetch next chunk
            const char* g = (const char*)codes_h + (size_t)(ct + 1) * 16384;
            char* l = (char*)&Bs[cur ^ 1][0];
            #pragma unroll
            for (int p = 0; p < 4; ++p) {
                const int off = (p * 256 + tid) * 16;
                __builtin_amdgcn_global_load_lds((g_void*)(g + off), (l_void*)(l + off), 16, 0, 0);
            }
        }

        const _Float16* bt = &Bs[cur][0] + lane * 8;
        v4f acc0 = (v4f){0.f, 0.f, 0.f, 0.f};
        v4f acc1 = (v4f){0.f, 0.f, 0.f, 0.f};
        #pragma unroll
        for (int kc = 0; kc < 8; ++kc) {
            half8 b0 = *(const half8*)(bt + kc * 512);
            half8 b1 = *(const half8*)(bt + 4096 + kc * 512);
            acc0 = __builtin_amdgcn_mfma_f32_16x16x32_f16(b0, xf[kc], acc0, 0, 0, 0);
            acc1 = __builtin_amdgcn_mfma_f32_16x16x32_f16(b1, xf[kc], acc1, 0, 0, 0);
        }

        // score = (cnorm + 1024) - 2*dot (positive); pack trunc-score|index
        const int cb = ct * 32 + quad * 4;
        float4 cn0 = *(const float4*)(cnormb + cb);
        float4 cn1 = *(const float4*)(cnormb + cb + 16);
        {
            const unsigned base = (unsigned)cb;
            unsigned k0 = (__float_as_uint(fmaf(-2.0f, acc0[0], cn0.x)) & 0xFFFFFC00u) | base;
            unsigned k1 = (__float_as_uint(fmaf(-2.0f, acc0[1], cn0.y)) & 0xFFFFFC00u) | (base + 1u);
            unsigned k2 = (__float_as_uint(fmaf(-2.0f, acc0[2], cn0.z)) & 0xFFFFFC00u) | (base + 2u);
            unsigned k3 = (__float_as_uint(fmaf(-2.0f, acc0[3], cn0.w)) & 0xFFFFFC00u) | (base + 3u);
            unsigned lo01 = umin_(k0, k1), hi01 = umax_(k0, k1);
            unsigned lo23 = umin_(k2, k3), hi23 = umax_(k2, k3);
            unsigned best = umin_(lo01, lo23);
            unsigned mid  = umax_(lo01, lo23);
            unsigned sec  = umin_(umin_(hi01, hi23), mid);
            unsigned tt   = umax_(K1, best);
            K2 = umin_(umin_(K2, sec), tt);
            K1 = umin_(K1, best);
        }
        {
            const unsigned base = (unsigned)(cb + 16);
            unsigned k0 = (__float_as_uint(fmaf(-2.0f, acc1[0], cn1.x)) & 0xFFFFFC00u) | base;
            unsigned k1 = (__float_as_uint(fmaf(-2.0f, acc1[1], cn1.y)) & 0xFFFFFC00u) | (base + 1u);
            unsigned k2 = (__float_as_uint(fmaf(-2.0f, acc1[2], cn1.z)) & 0xFFFFFC00u) | (base + 2u);
            unsigned k3 = (__float_as_uint(fmaf(-2.0f, acc1[3], cn1.w)) & 0xFFFFFC00u) | (base + 3u);
            unsigned lo01 = umin_(k0, k1), hi01 = umax_(k0, k1);
            unsigned lo23 = umin_(k2, k3), hi23 = umax_(k2, k3);
            unsigned best = umin_(lo01, lo23);
            unsigned mid  = umax_(lo01, lo23);
            unsigned sec  = umin_(umin_(hi01, hi23), mid);
            unsigned tt   = umax_(K1, best);
            K2 = umin_(umin_(K2, sec), tt);
            K1 = umin_(K1, best);
        }
        __syncthreads();   // Bs[cur] reads done before re-stage; next chunk landed
    }

    // merge the 4 quads (lanes l15, l15+16, l15+32, l15+48 hold the same row)
    #pragma unroll
    for (int off = 16; off < 64; off <<= 1) {
        unsigned o1 = (unsigned)__shfl_xor((int)K1, off, 64);
        unsigned o2 = (unsigned)__shfl_xor((int)K2, off, 64);
        unsigned tt = umax_(K1, o1);
        K2 = umin_(umin_(K2, o2), tt);
        K1 = umin_(K1, o1);
    }

    // winner + gap flag (quad 0 lanes own the 16 rows)
    if (lane < 16) {
        unsigned widx = K1 & 0x3FFu;
        out_i[myrow] = (float)widx;
        float g1 = __uint_as_float(K1 & 0xFFFFFC00u);
        float g2 = __uint_as_float(K2 & 0xFFFFFC00u);
        if (g2 - g1 < EPS1) {
            int s = atomicAdd(count1, 1);
            rowlist1[s] = myrow;
        }
    }

    // gather quantized rows: wave writes its own 16 rows, fully coalesced
    const float4* c4 = (const float4*)codes;
    float4* q4 = (float4*)out_q + (size_t)(row0 + wy * 16) * 64;
    #pragma unroll
    for (int r = 0; r < 16; ++r) {
        int wi = __shfl((int)K1, r, 64) & 0x3FF;   // lane r holds row r's winner
        q4[(size_t)r * 64 + lane] = c4[(size_t)wi * 64 + lane];
    }
}

// ---- tier-1: fp32 rescore of flagged rows, BR rows/block share codes stream ----
__global__ __launch_bounds__(256)
void rescue32(const float* __restrict__ x, const float* __restrict__ codes,
              const float* __restrict__ codes_t, const float* __restrict__ cnorm,
              const int* __restrict__ count1, const int* __restrict__ rowlist1,
              float* __restrict__ out_q, float* __restrict__ out_i,
              int* __restrict__ count2, int* __restrict__ rowlist2) {
    __shared__ __align__(16) float xr[BR][D];    // 8 KB
    __shared__ int rows_s[BR];
    __shared__ int winc_s[BR];
    __shared__ float wm1[BR][4], wm2[BR][4];
    __shared__ int wi_[BR][4];
    const int t = threadIdx.x;
    const int w = t >> 6, lane = t & 63;
    const int n1 = *count1;
    if (n1 == 0) return;
    const int nb = (n1 + BR - 1) / BR;
    const float4* ct4 = (const float4*)codes_t;  // [k][c/4]

    for (int b = blockIdx.x; b < nb; b += gridDim.x) {
        __syncthreads();
        if (t < BR) {
            int idx = b * BR + t;
            if (idx >= n1) idx = n1 - 1;           // duplicate tail rows (benign)
            rows_s[t] = rowlist1[idx];
        }
        __syncthreads();
        #pragma unroll
        for (int p = 0; p < BR * 64 / 256; ++p) {  // 2 iters
            int flat = p * 256 + t;
            int r = flat >> 6, q = flat & 63;
            ((float4*)&xr[r][0])[q] = ((const float4*)x)[(size_t)rows_s[r] * 64 + q];
        }
        __syncthreads();

        float acc[BR][4];                          // 32 VGPRs: fits, no spill
        #pragma unroll
        for (int r = 0; r < BR; ++r)
            #pragma unroll
            for (int j = 0; j < 4; ++j) acc[r][j] = 0.f;

        for (int k = 0; k < D; k += 4) {
            float4 cv0 = ct4[(size_t)(k+0) * 256 + t];
            float4 cv1 = ct4[(size_t)(k+1) * 256 + t];
            float4 cv2 = ct4[(size_t)(k+2) * 256 + t];
            float4 cv3 = ct4[(size_t)(k+3) * 256 + t];
            #pragma unroll
            for (int r = 0; r < BR; ++r) {
                float4 xv = *(const float4*)&xr[r][k];
                acc[r][0] = fmaf(xv.x, cv0.x, acc[r][0]);
                acc[r][1] = fmaf(xv.x, cv0.y, acc[r][1]);
                acc[r][2] = fmaf(xv.x, cv0.z, acc[r][2]);
                acc[r][3] = fmaf(xv.x, cv0.w, acc[r][3]);
                acc[r][0] = fmaf(xv.y, cv1.x, acc[r][0]);
                acc[r][1] = fmaf(xv.y, cv1.y, acc[r][1]);
                acc[r][2] = fmaf(xv.y, cv1.z, acc[r][2]);
                acc[r][3] = fmaf(xv.y, cv1.w, acc[r][3]);
                acc[r][0] = fmaf(xv.z, cv2.x, acc[r][0]);
                acc[r][1] = fmaf(xv.z, cv2.y, acc[r][1]);
                acc[r][2] = fmaf(xv.z, cv2.z, acc[r][2]);
                acc[r][3] = fmaf(xv.z, cv2.w, acc[r][3]);
                acc[r][0] = fmaf(xv.w, cv3.x, acc[r][0]);
                acc[r][1] = fmaf(xv.w, cv3.y, acc[r][1]);
                acc[r][2] = fmaf(xv.w, cv3.z, acc[r][2]);
                acc[r][3] = fmaf(xv.w, cv3.w, acc[r][3]);
            }
        }

        // per-thread top-2-of-4 + in-wave butterfly, all rows, no barriers
        float cn0 = cnorm[4*t+0], cn1 = cnorm[4*t+1], cn2 = cnorm[4*t+2], cn3 = cnorm[4*t+3];
        #pragma unroll
        for (int r = 0; r < BR; ++r) {
            float s0 = fmaf(-2.f, acc[r][0], cn0);
            float s1 = fmaf(-2.f, acc[r][1], cn1);
            float s2 = fmaf(-2.f, acc[r][2], cn2);
            float s3 = fmaf(-2.f, acc[r][3], cn3);
            float lm1 = s0; int li = 4*t;
            float lm2 = FLT_MAX;
            if (s1 < lm1) { lm2 = lm1; lm1 = s1; li = 4*t+1; } else lm2 = s1;
            if (s2 < lm1) { lm2 = lm1; lm1 = s2; li = 4*t+2; } else lm2 = fminf(lm2, s2);
            if (s3 < lm1) { lm2 = lm1; lm1 = s3; li = 4*t+3; } else lm2 = fminf(lm2, s3);
            #pragma unroll
            for (int off = 1; off < 64; off <<= 1) {
                float o1 = __shfl_xor(lm1, off, 64);
                float o2 = __shfl_xor(lm2, off, 64);
                int   oi = __shfl_xor(li,  off, 64);
                if (o1 < lm1 || (o1 == lm1 && oi < li)) { lm2 = fminf(lm1, o2); lm1 = o1; li = oi; }
                else lm2 = fminf(lm2, o1);
            }
            if (lane == 0) { wm1[r][w] = lm1; wm2[r][w] = lm2; wi_[r][w] = li; }
        }
        __syncthreads();
        if (t < BR) {
            float b1 = wm1[t][0], b2 = wm2[t][0]; int bi = wi_[t][0];
            #pragma unroll
            for (int ww = 1; ww < 4; ++ww) {
                float o1 = wm1[t][ww], o2 = wm2[t][ww]; int oi = wi_[t][ww];
                if (o1 < b1 || (o1 == b1 && oi < bi)) { b2 = fminf(b1, o2); b1 = o1; bi = oi; }
                else b2 = fminf(b2, o1);
            }
            const int rg = rows_s[t];
            out_i[rg] = (float)bi;
            winc_s[t] = bi;
            if (b2 - b1 < EPS2) {
                int s = atomicAdd(count2, 1);
                rowlist2[s] = rg;
            }
        }
        __syncthreads();
        // gather quantized rows
        #pragma unroll
        for (int p = 0; p < BR * 64 / 256; ++p) {
            int flat = p * 256 + t;
            int r = flat >> 6, q = flat & 63;
            float4 v = ((const float4*)codes)[(size_t)winc_s[r] * 64 + q];
            ((float4*)out_q)[(size_t)rows_s[r] * 64 + q] = v;
        }
        __syncthreads();
    }
}

// ---- tier-2: exact fp64 rescore; smallest index within DELTA ----
// COALESCED: codes values read via codes_t[k][4t..4t+3] (consecutive float4
// per lane) instead of codes[4t+j][k] (4096B lane stride, 64 lines/wave-load).
__global__ __launch_bounds__(256)
void rescue_exact(const float* __restrict__ x, const float* __restrict__ codes,
                  const float* __restrict__ codes_t,
                  const int* __restrict__ count, const int* __restrict__ rowlist,
                  float* __restrict__ out_q, float* __restrict__ out_i) {
    __shared__ float  xrow[D];
    __shared__ double dbuf[C];
    __shared__ double rmin[256];
    __shared__ int    ridx[256];
    const int t = threadIdx.x;
    const int n = *count;
    const float4* ct4 = (const float4*)codes_t;   // [k][c/4]
    for (int idx = blockIdx.x; idx < n; idx += gridDim.x) {
        const int row = rowlist[idx];
        __syncthreads();
        xrow[t] = x[(size_t)row * D + t];
        __syncthreads();
        // thread t owns codes 4t..4t+3; stream k with coalesced codes_t loads
        double s0 = 0.0, s1 = 0.0, s2 = 0.0, s3 = 0.0;
        #pragma unroll 4
        for (int k = 0; k < D; ++k) {
            float4 cv = ct4[(size_t)k * 256 + t];   // codes_t[k][4t..4t+3]
            double dx = (double)xrow[k];
            double d0 = dx - (double)cv.x;
            double d1 = dx - (double)cv.y;
            double d2 = dx - (double)cv.z;
            double d3 = dx - (double)cv.w;
            s0 += d0 * d0; s1 += d1 * d1; s2 += d2 * d2; s3 += d3 * d3;
        }
        dbuf[4*t+0] = s0; dbuf[4*t+1] = s1; dbuf[4*t+2] = s2; dbuf[4*t+3] = s3;
        double lmin = fmin(fmin(s0, s1), fmin(s2, s3));
        rmin[t] = lmin;
        __syncthreads();
        for (int sft = 128; sft > 0; sft >>= 1) {
            if (t < sft) rmin[t] = fmin(rmin[t], rmin[t + sft]);
            __syncthreads();
        }
        const double dstar = rmin[0];
        int lidx = INT_MAX;
        #pragma unroll
        for (int j = 0; j < 4; ++j) {
            const int c = 4 * t + j;
            if (dbuf[c] < dstar + DELTA && c < lidx) lidx = c;
        }
        ridx[t] = lidx;
        __syncthreads();
        for (int sft = 128; sft > 0; sft >>= 1) {
            if (t < sft) ridx[t] = min(ridx[t], ridx[t + sft]);
            __syncthreads();
        }
        const int winc = ridx[0];
        if (t == 0) out_i[row] = (float)winc;
        if (t < 64) {
            float4 cv = ((const float4*)(codes + (size_t)winc * D))[t];
            ((float4*)(out_q + (size_t)row * D))[t] = cv;
        }
        __syncthreads();
    }
}

extern "C" void kernel_launch(void* const* d_in, const int* in_sizes, int n_in,
                              void* d_out, int out_size, void* d_ws, size_t ws_size,
                              hipStream_t stream) {
    const float* x     = (const float*)d_in[0];
    const float* codes = (const float*)d_in[1];
    const int N = in_sizes[0] / D;                 // 65536

    char* ws = (char*)d_ws;
    float*    cnorm   = (float*)ws;                       ws += C * 4;              // 4 KB
    float*    cnormb  = (float*)ws;                       ws += C * 4;              // 4 KB (biased +1024)
    float*    codes_t = (float*)ws;                       ws += (size_t)D * C * 4;  // 1 MB
    _Float16* codes_h = (_Float16*)ws;                    ws += (size_t)C * D * 2;  // 512 KB (tiled)
    int*      count1  = (int*)ws;                         ws += 16;
    int*      count2  = (int*)ws;                         ws += 16;
    int*      rowlist1 = (int*)ws;                        ws += (size_t)N * 4;
    int*      rowlist2 = (int*)ws;

    float* out_q = (float*)d_out;
    float* out_i = out_q + (size_t)N * D;

    prep<<<C / 4, 256, 0, stream>>>(codes, cnorm, cnormb, codes_h, codes_t, count1, count2);
    codebook_mfma<<<N / 64, 256, 0, stream>>>(x, codes_h, codes, cnormb,
                                              out_q, out_i, count1, rowlist1);
    rescue32<<<512, 256, 0, stream>>>(x, codes, codes_t, cnorm, count1, rowlist1,
                                      out_q, out_i, count2, rowlist2);
    rescue_exact<<<1024, 256, 0, stream>>>(x, codes, codes_t, count2, rowlist2,
                                           out_q, out_i);
}